// Round 7
// baseline (259.563 us; speedup 1.0000x reference)
//
#include <hip/hip_runtime.h>

typedef unsigned short u16;
typedef unsigned short u16x4 __attribute__((ext_vector_type(4)));
typedef unsigned short u16x8 __attribute__((ext_vector_type(8)));
typedef short bf16x8 __attribute__((ext_vector_type(8)));
typedef float f32x4 __attribute__((ext_vector_type(4)));

#define EPSF 1e-5f

// Geometry
#define NB   64
#define C1   512
#define C2   128
#define C3   32
#define HH   28
#define WW   28
#define HW   784            // 28*28
#define NHW  50176          // 64*784
#define XELEMS 25690112     // 64*512*784
#define K1_BLOCKS 2048
#define CONV1_BLOCKS 392    // NHW/128
#define CONV2_BLOCKS 784    // NHW/64
#define K2Q_BLOCKS 3136     // 50176*128/(8*256)

// ws layout (bytes)
#define WS_BN1I   64        // 512 f32
#define WS_BN1B   2112      // 512 f32
#define WS_BN2I   4160      // 128 f32
#define WS_BN2B   4672      // 128 f32
#define WS_WQ1    5376      // 128*512 bf16   -> ends 136448
#define WS_WQ2    136448    // 9*32*128 bf16  -> ends 210176
#define WS_P1     210176    // 2048 float2 partials (k1)   -> ends 226560
#define WS_P2     226560    // 392 float2 partials (conv1) -> ends 229696
#define WS_PW1    232832    // 64 float2 partials (w1)
#define WS_PW2    233344    // 16 float2 partials (w2)
#define WS_H2     233472    // 50176*128 bf16 (NHWC)

__device__ __forceinline__ float bf2f(u16 u) { return __uint_as_float(((unsigned)u) << 16); }
__device__ __forceinline__ u16 f2bf(float f) {
  unsigned x = __float_as_uint(f);
  return (u16)((x + 0x7fffu + ((x >> 16) & 1u)) >> 16);
}
__device__ __forceinline__ float finz(float f) {
  unsigned u = __float_as_uint(f);
  return ((u & 0x7f800000u) == 0x7f800000u) ? 0.0f : f;
}

// block-level min/max reduce; result valid on threadIdx.x==0
__device__ __forceinline__ void block_minmax(float& mn, float& mx) {
  for (int m = 32; m; m >>= 1) {
    mn = fminf(mn, __shfl_xor(mn, m));
    mx = fmaxf(mx, __shfl_xor(mx, m));
  }
  __shared__ float wmn[4], wmx[4];
  const int wv = threadIdx.x >> 6;
  if ((threadIdx.x & 63) == 0) { wmn[wv] = mn; wmx[wv] = mx; }
  __syncthreads();
  if (threadIdx.x == 0) {
    mn = fminf(fminf(wmn[0], wmn[1]), fminf(wmn[2], wmn[3]));
    mx = fmaxf(fmaxf(wmx[0], wmx[1]), fmaxf(wmx[2], wmx[3]));
  }
}

// ---------------------------------------------------------------------------
// kwA: BN tables + w1/w2 min/max partials.  81 blocks x 256.
// ---------------------------------------------------------------------------
__global__ __launch_bounds__(256) void kwA_kernel(const float* g1, const float* be1,
                                                  const float* m1, const float* v1,
                                                  const float* w1,
                                                  const float* g2, const float* be2,
                                                  const float* m2, const float* v2,
                                                  const float* w2, unsigned char* ws) {
  const int t = threadIdx.x;
  const int b = blockIdx.x;
  float2* pw1 = (float2*)(ws + WS_PW1);
  float2* pw2 = (float2*)(ws + WS_PW2);

  if (b == 80) {
    float* bn1i = (float*)(ws + WS_BN1I);
    float* bn1b = (float*)(ws + WS_BN1B);
    float* bn2i = (float*)(ws + WS_BN2I);
    float* bn2b = (float*)(ws + WS_BN2B);
    for (int c = t; c < C1; c += 256) {
      float inv = g1[c] / sqrtf(v1[c] + EPSF);
      bn1i[c] = inv;
      bn1b[c] = be1[c] - m1[c] * inv;
    }
    if (t < C2) {
      float inv = g2[t] / sqrtf(v2[t] + EPSF);
      bn2i[t] = inv;
      bn2b[t] = be2[t] - m2[t] * inv;
    }
    return;
  }

  float mn = 3.4e38f, mx = -3.4e38f;
  if (b < 64) {
    f32x4 v = *(const f32x4*)(w1 + b * 1024 + t * 4);
#pragma unroll
    for (int j = 0; j < 4; j++) {
      float f = finz(v[j]); mn = fminf(mn, f); mx = fmaxf(mx, f);
    }
    block_minmax(mn, mx);
    if (t == 0) pw1[b] = make_float2(mn, mx);
  } else {
    const int base = (b - 64) * 2304;
#pragma unroll
    for (int j = 0; j < 9; j++) {
      float f = finz(w2[base + t + j * 256]); mn = fminf(mn, f); mx = fmaxf(mx, f);
    }
    block_minmax(mn, mx);
    if (t == 0) pw2[b - 64] = make_float2(mn, mx);
  }
}

// ---------------------------------------------------------------------------
// kwB: reduce weight partials, quantize w1 -> wq1, quantize+pack w2 -> wq2.
// ---------------------------------------------------------------------------
__global__ __launch_bounds__(256) void kwB_kernel(const float* w1, const float* w2,
                                                  unsigned char* ws) {
  const float2* pw1 = (const float2*)(ws + WS_PW1);
  const float2* pw2 = (const float2*)(ws + WS_PW2);
  u16* wq1 = (u16*)(ws + WS_WQ1);
  u16* wq2 = (u16*)(ws + WS_WQ2);
  const int t = threadIdx.x;
  const int b = blockIdx.x;
  __shared__ float bc[2];

  if (b < 64) {
    if (t < 64) {
      float2 p = pw1[t];
      float mn = p.x, mx = p.y;
      for (int m = 32; m; m >>= 1) {
        mn = fminf(mn, __shfl_xor(mn, m));
        mx = fmaxf(mx, __shfl_xor(mx, m));
      }
      if (t == 0) { bc[0] = mn; bc[1] = mx; }
    }
    __syncthreads();
    const float mn = bc[0];
    const float s = fmaxf((bc[1] - mn) / 255.0f, 1e-8f);
    const float rs = 1.0f / s;
    f32x4 v = *(const f32x4*)(w1 + b * 1024 + t * 4);
    u16x4 o;
#pragma unroll
    for (int j = 0; j < 4; j++)
      o[j] = f2bf(fmaf(rintf((finz(v[j]) - mn) * rs), s, mn));
    *(u16x4*)(wq1 + b * 1024 + t * 4) = o;
  } else {
    if (t < 64) {
      float2 p = (t < 16) ? pw2[t] : make_float2(3.4e38f, -3.4e38f);
      float mn = p.x, mx = p.y;
      for (int m = 32; m; m >>= 1) {
        mn = fminf(mn, __shfl_xor(mn, m));
        mx = fmaxf(mx, __shfl_xor(mx, m));
      }
      if (t == 0) { bc[0] = mn; bc[1] = mx; }
    }
    __syncthreads();
    const float mn = bc[0];
    const float s = fmaxf((bc[1] - mn) / 255.0f, 1e-8f);
    const float rs = 1.0f / s;
    const int base = (b - 64) * 2304;
#pragma unroll
    for (int j = 0; j < 9; j++) {
      int o = base + t + j * 256;       // o = tap*4096 + co*128 + ci
      int tap = o >> 12;
      int rem = o & 4095;
      float f = finz(w2[rem * 9 + tap]);
      wq2[o] = f2bf(fmaf(rintf((f - mn) * rs), s, mn));
    }
  }
}

// ---------------------------------------------------------------------------
// K1: min/max of relu(bn1(x)).  2048 blocks -> partials.
// ---------------------------------------------------------------------------
__global__ __launch_bounds__(256) void k1_minmax(const float* __restrict__ x, unsigned char* ws) {
  const float* bn1i = (const float*)(ws + WS_BN1I);
  const float* bn1b = (const float*)(ws + WS_BN1B);
  float2* p1 = (float2*)(ws + WS_P1);
  int gid = blockIdx.x * blockDim.x + threadIdx.x;
  int stride = gridDim.x * blockDim.x;
  const int ngroups = XELEMS / 4;
  float mn = 3.4e38f, mx = 0.0f;
  for (int i = gid; i < ngroups; i += stride) {
    int base = i * 4;
    int c = (base / HW) & (C1 - 1);
    float inv = bn1i[c], bb = bn1b[c];
    f32x4 u = *((const f32x4*)x + i);
#pragma unroll
    for (int j = 0; j < 4; j++) {
      float f = fmaxf(fmaf(u[j], inv, bb), 0.0f);
      mn = fminf(mn, f); mx = fmaxf(mx, f);
    }
  }
  block_minmax(mn, mx);
  if (threadIdx.x == 0) p1[blockIdx.x] = make_float2(mn, mx);
}

// ---------------------------------------------------------------------------
// conv1: 1x1 conv MFMA GEMM, tile 128co x 128sp, 392 blocks, swizzled LDS.
// Element (row,k) at row*40 + (k&7) + 8*(((k>>3)+(row>>3))&3).
// Epilogue: bn2+relu -> h2 raw bf16 NHWC + per-block min/max partial.
// ---------------------------------------------------------------------------
__global__ __launch_bounds__(256) void conv1_kernel(const float* __restrict__ x,
                                                    unsigned char* ws) {
  const float* bn1i = (const float*)(ws + WS_BN1I);
  const float* bn1b = (const float*)(ws + WS_BN1B);
  const float* bn2i = (const float*)(ws + WS_BN2I);
  const float* bn2b = (const float*)(ws + WS_BN2B);
  const u16* wq1 = (const u16*)(ws + WS_WQ1);
  const float2* p1 = (const float2*)(ws + WS_P1);
  float2* p2 = (float2*)(ws + WS_P2);
  u16* h2 = (u16*)(ws + WS_H2);

  __shared__ __align__(16) u16 Alds[128 * 40];
  __shared__ __align__(16) u16 Blds[128 * 40];
  __shared__ float bc[2];
  __shared__ float wred[8];

  const int t = threadIdx.x;
  const int sp0 = blockIdx.x * 128;

  // preamble: reduce 2048 k1-partials (read as 1024 f32x4)
  {
    const f32x4* p4 = (const f32x4*)p1;
    float mn = 3.4e38f, mx = 0.0f;
#pragma unroll
    for (int i = 0; i < 4; i++) {
      f32x4 v = p4[t + i * 256];
      mn = fminf(mn, fminf(v[0], v[2]));
      mx = fmaxf(mx, fmaxf(v[1], v[3]));
    }
    block_minmax(mn, mx);
    if (t == 0) { bc[0] = mn; bc[1] = mx; }
    __syncthreads();
  }
  const float mn1 = bc[0];
  const float s1 = fmaxf((bc[1] - mn1) / 255.0f, 1e-8f);
  const float r1 = 1.0f / s1;

  // x staging: thread -> k-row kk (0..31), sp groups of 8 in both halves
  const int kk = t >> 3;
  const int spA = (t & 7) * 8;
  const int spB = 64 + spA;
  const int ga = sp0 + spA, gb = sp0 + spB;
  const int na = ga / HW, hwa = ga % HW;
  const int nb = gb / HW, hwb = gb % HW;
  const float* xA = x + na * (C1 * HW) + hwa;
  const float* xB = x + nb * (C1 * HW) + hwb;
  // swizzled column for this thread's (kk, sp-group); same for spA and spB
  const int colg = (kk & 7) + 8 * ((((kk >> 3) + (spA >> 3))) & 3);

  // wq1 staging: thread -> co = t>>1, k offset (t&1)*16
  const int wco = t >> 1;
  const int wko = (t & 1) * 16;
  const int ab0 = wko >> 3;
  const int aswz = (wco >> 3) & 3;

  const int lane = t & 63;
  const int l15 = lane & 15;
  const int q = lane >> 4;
  const int wv = t >> 6;
  const int wy = wv >> 1;   // co half
  const int wx = wv & 1;    // sp half

  f32x4 acc[4][4] = {};

  for (int k0 = 0; k0 < C1; k0 += 32) {
    __syncthreads();
    {  // stage wq1 slice [128co x 32k], swizzled
      const u16* src = wq1 + wco * C1 + k0 + wko;
      u16x8 a0 = *(const u16x8*)(src);
      u16x8 a1 = *(const u16x8*)(src + 8);
      *(u16x8*)&Alds[wco * 40 + (((ab0 + 0 + aswz) & 3) << 3)] = a0;
      *(u16x8*)&Alds[wco * 40 + (((ab0 + 1 + aswz) & 3) << 3)] = a1;
    }
    {  // stage x slice [32k x 128sp]: bn1+relu+quant, swizzled transpose
      int c = k0 + kk;
      float inv = bn1i[c], bb = bn1b[c];
      f32x4 va0 = *(const f32x4*)(xA + c * HW);
      f32x4 va1 = *(const f32x4*)(xA + c * HW + 4);
      f32x4 vb0 = *(const f32x4*)(xB + c * HW);
      f32x4 vb1 = *(const f32x4*)(xB + c * HW + 4);
#pragma unroll
      for (int j = 0; j < 4; j++) {
        float f0 = fmaxf(fmaf(va0[j], inv, bb), 0.0f);
        Blds[(spA + j) * 40 + colg] = f2bf(fmaf(rintf((f0 - mn1) * r1), s1, mn1));
        float f1 = fmaxf(fmaf(va1[j], inv, bb), 0.0f);
        Blds[(spA + 4 + j) * 40 + colg] = f2bf(fmaf(rintf((f1 - mn1) * r1), s1, mn1));
        float g0 = fmaxf(fmaf(vb0[j], inv, bb), 0.0f);
        Blds[(spB + j) * 40 + colg] = f2bf(fmaf(rintf((g0 - mn1) * r1), s1, mn1));
        float g1v = fmaxf(fmaf(vb1[j], inv, bb), 0.0f);
        Blds[(spB + 4 + j) * 40 + colg] = f2bf(fmaf(rintf((g1v - mn1) * r1), s1, mn1));
      }
    }
    __syncthreads();
    bf16x8 af[4], bfr[4];
#pragma unroll
    for (int i = 0; i < 4; i++) {
      int R = wy * 64 + i * 16 + l15;
      af[i] = *(const bf16x8*)&Alds[R * 40 + (((q + (R >> 3)) & 3) << 3)];
    }
#pragma unroll
    for (int j = 0; j < 4; j++) {
      int R = wx * 64 + j * 16 + l15;
      bfr[j] = *(const bf16x8*)&Blds[R * 40 + (((q + (R >> 3)) & 3) << 3)];
    }
#pragma unroll
    for (int i = 0; i < 4; i++)
#pragma unroll
      for (int j = 0; j < 4; j++)
        acc[i][j] = __builtin_amdgcn_mfma_f32_16x16x32_bf16(af[i], bfr[j], acc[i][j], 0, 0, 0);
  }

  // epilogue: bn2 + relu, store raw h2 NHWC bf16, per-block min/max partial
  float lmn = 3.4e38f, lmx = 0.0f;
#pragma unroll
  for (int i = 0; i < 4; i++) {
    int cob = wy * 64 + i * 16 + q * 4;
    f32x4 i2 = *(const f32x4*)&bn2i[cob];
    f32x4 b2 = *(const f32x4*)&bn2b[cob];
#pragma unroll
    for (int j = 0; j < 4; j++) {
      int sp = sp0 + wx * 64 + j * 16 + l15;
      u16x4 v;
#pragma unroll
      for (int r = 0; r < 4; r++) {
        float h = fmaxf(fmaf(acc[i][j][r], i2[r], b2[r]), 0.0f);
        v[r] = f2bf(h);
        lmn = fminf(lmn, h); lmx = fmaxf(lmx, h);
      }
      *(u16x4*)&h2[sp * C2 + cob] = v;
    }
  }
  for (int m = 32; m; m >>= 1) {
    lmn = fminf(lmn, __shfl_xor(lmn, m));
    lmx = fmaxf(lmx, __shfl_xor(lmx, m));
  }
  if (lane == 0) { wred[wv] = lmn; wred[4 + wv] = lmx; }
  __syncthreads();
  if (t == 0) {
    float2 pr;
    pr.x = fminf(fminf(wred[0], wred[1]), fminf(wred[2], wred[3]));
    pr.y = fmaxf(fmaxf(wred[4], wred[5]), fmaxf(wred[6], wred[7]));
    p2[blockIdx.x] = pr;
  }
}

// ---------------------------------------------------------------------------
// k2q: quantize h2 in place (bf16 -> quantized bf16).  3136 blocks x 256.
// ---------------------------------------------------------------------------
__global__ __launch_bounds__(256) void k2q_kernel(unsigned char* ws) {
  u16* h2 = (u16*)(ws + WS_H2);
  const float2* p2 = (const float2*)(ws + WS_P2);
  __shared__ float bc[2];
  const int t = threadIdx.x;
  {
    float mn = 3.4e38f, mx = 0.0f;
    for (int i = t; i < CONV1_BLOCKS; i += 256) {
      float2 p = p2[i];
      mn = fminf(mn, p.x); mx = fmaxf(mx, p.y);
    }
    block_minmax(mn, mx);
    if (t == 0) { bc[0] = mn; bc[1] = mx; }
    __syncthreads();
  }
  const float mn2 = bc[0];
  const float s2 = fmaxf((bc[1] - mn2) / 255.0f, 1e-8f);
  const float r2 = 1.0f / s2;

  const int idx = blockIdx.x * 256 + t;
  u16x8 v = ((u16x8*)h2)[idx];
  u16x8 o;
#pragma unroll
  for (int j = 0; j < 8; j++) {
    float h = bf2f(v[j]);
    o[j] = f2bf(fmaf(rintf((h - mn2) * r2), s2, mn2));
  }
  ((u16x8*)h2)[idx] = o;
}

// ---------------------------------------------------------------------------
// conv2: 3x3 conv (pad 1) direct MFMA over pre-quantized h2.  784 blocks,
// wave = 32co x 16sp.  Pure load+MFMA inner loop.
// ---------------------------------------------------------------------------
__global__ __launch_bounds__(256) void conv2_kernel(const unsigned char* ws,
                                                    float* __restrict__ out) {
  const u16* wq2 = (const u16*)(ws + WS_WQ2);
  const u16* h2 = (const u16*)(ws + WS_H2);

  const int t = threadIdx.x;
  const int lane = t & 63;
  const int l15 = lane & 15;
  const int q = lane >> 4;
  const int wv = t >> 6;

  const int spf = blockIdx.x * 64 + wv * 16 + l15;
  const int nn = spf / HW;
  const int hwf = spf % HW;
  const int hf = hwf / WW;
  const int wf = hwf % WW;

  f32x4 acc[2] = {};
  bf16x8 bz;
#pragma unroll
  for (int j = 0; j < 8; j++) bz[j] = 0;

  for (int tap = 0; tap < 9; tap++) {
    const int dh = tap / 3 - 1, dw = tap % 3 - 1;
    const u16* wA = wq2 + tap * (C3 * C2);
    unsigned h2i = (unsigned)(hf + dh);
    unsigned w2i = (unsigned)(wf + dw);
    const bool val = (h2i < 28u) && (w2i < 28u);
    const u16* bptr = h2 + ((size_t)(nn * HW + (int)h2i * WW + (int)w2i)) * C2;
#pragma unroll
    for (int ks = 0; ks < C2; ks += 32) {
      bf16x8 a[2], b;
#pragma unroll
      for (int f = 0; f < 2; f++)
        a[f] = *(const bf16x8*)(wA + (f * 16 + l15) * C2 + ks + q * 8);
      b = val ? *(const bf16x8*)(bptr + ks + q * 8) : bz;
#pragma unroll
      for (int i = 0; i < 2; i++)
        acc[i] = __builtin_amdgcn_mfma_f32_16x16x32_bf16(a[i], b, acc[i], 0, 0, 0);
    }
  }

#pragma unroll
  for (int i = 0; i < 2; i++) {
    int co = i * 16 + q * 4;
#pragma unroll
    for (int r = 0; r < 4; r++)
      out[(nn * C3 + co + r) * HW + hwf] = acc[i][r];
  }
}

// ---------------------------------------------------------------------------
extern "C" void kernel_launch(void* const* d_in, const int* in_sizes, int n_in,
                              void* d_out, int out_size, void* d_ws, size_t ws_size,
                              hipStream_t stream) {
  const float* x  = (const float*)d_in[0];
  const float* g1 = (const float*)d_in[1];
  const float* b1 = (const float*)d_in[2];
  const float* m1 = (const float*)d_in[3];
  const float* v1 = (const float*)d_in[4];
  const float* w1 = (const float*)d_in[5];
  const float* g2 = (const float*)d_in[6];
  const float* b2 = (const float*)d_in[7];
  const float* m2 = (const float*)d_in[8];
  const float* v2 = (const float*)d_in[9];
  const float* w2 = (const float*)d_in[10];
  unsigned char* ws = (unsigned char*)d_ws;
  float* out = (float*)d_out;

  kwA_kernel<<<81, 256, 0, stream>>>(g1, b1, m1, v1, w1, g2, b2, m2, v2, w2, ws);
  kwB_kernel<<<80, 256, 0, stream>>>(w1, w2, ws);
  k1_minmax<<<K1_BLOCKS, 256, 0, stream>>>(x, ws);
  conv1_kernel<<<CONV1_BLOCKS, 256, 0, stream>>>(x, ws);
  k2q_kernel<<<K2Q_BLOCKS, 256, 0, stream>>>(ws);
  conv2_kernel<<<CONV2_BLOCKS, 256, 0, stream>>>(ws, out);
}

// Round 8
// 247.516 us; speedup vs baseline: 1.0487x; 1.0487x over previous
//
#include <hip/hip_runtime.h>

typedef unsigned short u16;
typedef unsigned short u16x4 __attribute__((ext_vector_type(4)));
typedef unsigned short u16x8 __attribute__((ext_vector_type(8)));
typedef short bf16x8 __attribute__((ext_vector_type(8)));
typedef float f32x4 __attribute__((ext_vector_type(4)));

#define EPSF 1e-5f

// Geometry
#define NB   64
#define C1   512
#define C2   128
#define C3   32
#define HH   28
#define WW   28
#define HW   784            // 28*28
#define NHW  50176          // 64*784
#define XELEMS 25690112     // 64*512*784
#define K1_BLOCKS 2048
#define CONV1_BLOCKS 392    // NHW/128
#define CONV2_BLOCKS 784    // NHW/64

// ws layout (bytes)
#define WS_BN1I   64        // 512 f32
#define WS_BN1B   2112      // 512 f32
#define WS_BN2I   4160      // 128 f32
#define WS_BN2B   4672      // 128 f32
#define WS_WQ1    5376      // 128*512 bf16   -> ends 136448
#define WS_WQ2    136448    // 9*32*128 bf16  -> ends 210176
#define WS_P1     210176    // 2048 float2 partials (k1)   -> ends 226560
#define WS_P2     226560    // 392 float2 partials (conv1) -> ends 229696
#define WS_PW1    232832    // 64 float2 partials (w1)
#define WS_PW2    233344    // 16 float2 partials (w2)
#define WS_H2     233472    // 50176*128 bf16 (NHWC)

__device__ __forceinline__ float bf2f(u16 u) { return __uint_as_float(((unsigned)u) << 16); }
__device__ __forceinline__ u16 f2bf(float f) {
  unsigned x = __float_as_uint(f);
  return (u16)((x + 0x7fffu + ((x >> 16) & 1u)) >> 16);
}
__device__ __forceinline__ float finz(float f) {
  unsigned u = __float_as_uint(f);
  return ((u & 0x7f800000u) == 0x7f800000u) ? 0.0f : f;
}

// block-level min/max reduce; result valid on threadIdx.x==0
__device__ __forceinline__ void block_minmax(float& mn, float& mx) {
  for (int m = 32; m; m >>= 1) {
    mn = fminf(mn, __shfl_xor(mn, m));
    mx = fmaxf(mx, __shfl_xor(mx, m));
  }
  __shared__ float wmn[4], wmx[4];
  const int wv = threadIdx.x >> 6;
  if ((threadIdx.x & 63) == 0) { wmn[wv] = mn; wmx[wv] = mx; }
  __syncthreads();
  if (threadIdx.x == 0) {
    mn = fminf(fminf(wmn[0], wmn[1]), fminf(wmn[2], wmn[3]));
    mx = fmaxf(fmaxf(wmx[0], wmx[1]), fmaxf(wmx[2], wmx[3]));
  }
}

// ---------------------------------------------------------------------------
// kwA: BN tables + w1/w2 min/max partials.  81 blocks x 256.
// ---------------------------------------------------------------------------
__global__ __launch_bounds__(256) void kwA_kernel(const float* g1, const float* be1,
                                                  const float* m1, const float* v1,
                                                  const float* w1,
                                                  const float* g2, const float* be2,
                                                  const float* m2, const float* v2,
                                                  const float* w2, unsigned char* ws) {
  const int t = threadIdx.x;
  const int b = blockIdx.x;
  float2* pw1 = (float2*)(ws + WS_PW1);
  float2* pw2 = (float2*)(ws + WS_PW2);

  if (b == 80) {
    float* bn1i = (float*)(ws + WS_BN1I);
    float* bn1b = (float*)(ws + WS_BN1B);
    float* bn2i = (float*)(ws + WS_BN2I);
    float* bn2b = (float*)(ws + WS_BN2B);
    for (int c = t; c < C1; c += 256) {
      float inv = g1[c] / sqrtf(v1[c] + EPSF);
      bn1i[c] = inv;
      bn1b[c] = be1[c] - m1[c] * inv;
    }
    if (t < C2) {
      float inv = g2[t] / sqrtf(v2[t] + EPSF);
      bn2i[t] = inv;
      bn2b[t] = be2[t] - m2[t] * inv;
    }
    return;
  }

  float mn = 3.4e38f, mx = -3.4e38f;
  if (b < 64) {
    f32x4 v = *(const f32x4*)(w1 + b * 1024 + t * 4);
#pragma unroll
    for (int j = 0; j < 4; j++) {
      float f = finz(v[j]); mn = fminf(mn, f); mx = fmaxf(mx, f);
    }
    block_minmax(mn, mx);
    if (t == 0) pw1[b] = make_float2(mn, mx);
  } else {
    const int base = (b - 64) * 2304;
#pragma unroll
    for (int j = 0; j < 9; j++) {
      float f = finz(w2[base + t + j * 256]); mn = fminf(mn, f); mx = fmaxf(mx, f);
    }
    block_minmax(mn, mx);
    if (t == 0) pw2[b - 64] = make_float2(mn, mx);
  }
}

// ---------------------------------------------------------------------------
// kwB: reduce weight partials, quantize w1 -> wq1, quantize+pack w2 -> wq2.
// ---------------------------------------------------------------------------
__global__ __launch_bounds__(256) void kwB_kernel(const float* w1, const float* w2,
                                                  unsigned char* ws) {
  const float2* pw1 = (const float2*)(ws + WS_PW1);
  const float2* pw2 = (const float2*)(ws + WS_PW2);
  u16* wq1 = (u16*)(ws + WS_WQ1);
  u16* wq2 = (u16*)(ws + WS_WQ2);
  const int t = threadIdx.x;
  const int b = blockIdx.x;
  __shared__ float bc[2];

  if (b < 64) {
    if (t < 64) {
      float2 p = pw1[t];
      float mn = p.x, mx = p.y;
      for (int m = 32; m; m >>= 1) {
        mn = fminf(mn, __shfl_xor(mn, m));
        mx = fmaxf(mx, __shfl_xor(mx, m));
      }
      if (t == 0) { bc[0] = mn; bc[1] = mx; }
    }
    __syncthreads();
    const float mn = bc[0];
    const float s = fmaxf((bc[1] - mn) / 255.0f, 1e-8f);
    const float rs = 1.0f / s;
    f32x4 v = *(const f32x4*)(w1 + b * 1024 + t * 4);
    u16x4 o;
#pragma unroll
    for (int j = 0; j < 4; j++)
      o[j] = f2bf(fmaf(rintf((finz(v[j]) - mn) * rs), s, mn));
    *(u16x4*)(wq1 + b * 1024 + t * 4) = o;
  } else {
    if (t < 64) {
      float2 p = (t < 16) ? pw2[t] : make_float2(3.4e38f, -3.4e38f);
      float mn = p.x, mx = p.y;
      for (int m = 32; m; m >>= 1) {
        mn = fminf(mn, __shfl_xor(mn, m));
        mx = fmaxf(mx, __shfl_xor(mx, m));
      }
      if (t == 0) { bc[0] = mn; bc[1] = mx; }
    }
    __syncthreads();
    const float mn = bc[0];
    const float s = fmaxf((bc[1] - mn) / 255.0f, 1e-8f);
    const float rs = 1.0f / s;
    const int base = (b - 64) * 2304;
#pragma unroll
    for (int j = 0; j < 9; j++) {
      int o = base + t + j * 256;       // o = tap*4096 + co*128 + ci
      int tap = o >> 12;
      int rem = o & 4095;
      float f = finz(w2[rem * 9 + tap]);
      wq2[o] = f2bf(fmaf(rintf((f - mn) * rs), s, mn));
    }
  }
}

// ---------------------------------------------------------------------------
// K1: min/max of relu(bn1(x)).  2048 blocks -> partials.
// ---------------------------------------------------------------------------
__global__ __launch_bounds__(256) void k1_minmax(const float* __restrict__ x, unsigned char* ws) {
  const float* bn1i = (const float*)(ws + WS_BN1I);
  const float* bn1b = (const float*)(ws + WS_BN1B);
  float2* p1 = (float2*)(ws + WS_P1);
  int gid = blockIdx.x * blockDim.x + threadIdx.x;
  int stride = gridDim.x * blockDim.x;
  const int ngroups = XELEMS / 4;
  float mn = 3.4e38f, mx = 0.0f;
  for (int i = gid; i < ngroups; i += stride) {
    int base = i * 4;
    int c = (base / HW) & (C1 - 1);
    float inv = bn1i[c], bb = bn1b[c];
    f32x4 u = *((const f32x4*)x + i);
#pragma unroll
    for (int j = 0; j < 4; j++) {
      float f = fmaxf(fmaf(u[j], inv, bb), 0.0f);
      mn = fminf(mn, f); mx = fmaxf(mx, f);
    }
  }
  block_minmax(mn, mx);
  if (threadIdx.x == 0) p1[blockIdx.x] = make_float2(mn, mx);
}

// ---------------------------------------------------------------------------
// conv1: 1x1 conv MFMA GEMM, tile 128co x 128sp, DOUBLE-BUFFERED LDS with
// one barrier per K-iter: loads for k+1 issue before the barrier and are
// consumed after the MFMA phase, hiding HBM latency.
// LDS swizzle: element (row,k) at row*40 + (k&7) + 8*(((k>>3)+(row>>3))&3).
// ---------------------------------------------------------------------------
__global__ __launch_bounds__(256) void conv1_kernel(const float* __restrict__ x,
                                                    unsigned char* ws) {
  const float* bn1i = (const float*)(ws + WS_BN1I);
  const float* bn1b = (const float*)(ws + WS_BN1B);
  const float* bn2i = (const float*)(ws + WS_BN2I);
  const float* bn2b = (const float*)(ws + WS_BN2B);
  const u16* wq1 = (const u16*)(ws + WS_WQ1);
  const float2* p1 = (const float2*)(ws + WS_P1);
  float2* p2 = (float2*)(ws + WS_P2);
  u16* h2 = (u16*)(ws + WS_H2);

  __shared__ __align__(16) u16 Alds[2][128 * 40];
  __shared__ __align__(16) u16 Blds[2][128 * 40];
  __shared__ float bc[2];
  __shared__ float wred[8];

  const int t = threadIdx.x;
  const int sp0 = blockIdx.x * 128;

  // preamble: reduce 2048 k1-partials (read as 1024 f32x4); scratch = Alds
  {
    float* rmn = (float*)&Alds[0][0];
    float* rmx = (float*)&Blds[0][0];
    const f32x4* p4 = (const f32x4*)p1;
    float mn = 3.4e38f, mx = 0.0f;
#pragma unroll
    for (int i = 0; i < 4; i++) {
      f32x4 v = p4[t + i * 256];
      mn = fminf(mn, fminf(v[0], v[2]));
      mx = fmaxf(mx, fmaxf(v[1], v[3]));
    }
    rmn[t] = mn; rmx[t] = mx;
    __syncthreads();
    for (int s = 128; s > 0; s >>= 1) {
      if (t < s) { rmn[t] = fminf(rmn[t], rmn[t + s]); rmx[t] = fmaxf(rmx[t], rmx[t + s]); }
      __syncthreads();
    }
    if (t == 0) { bc[0] = rmn[0]; bc[1] = rmx[0]; }
    __syncthreads();
  }
  const float mn1 = bc[0];
  const float s1 = fmaxf((bc[1] - mn1) / 255.0f, 1e-8f);
  const float r1 = 1.0f / s1;

  // x staging: thread -> k-row kk (0..31), sp groups of 8 in both halves
  const int kk = t >> 3;
  const int spA = (t & 7) * 8;
  const int spB = 64 + spA;
  const int ga = sp0 + spA, gb = sp0 + spB;
  const int na = ga / HW, hwa = ga % HW;
  const int nb = gb / HW, hwb = gb % HW;
  const float* xA = x + na * (C1 * HW) + hwa;
  const float* xB = x + nb * (C1 * HW) + hwb;
  const int colg = (kk & 7) + 8 * ((((kk >> 3) + (spA >> 3))) & 3);

  // wq1 staging: thread -> co = t>>1, k offset (t&1)*16
  const int wco = t >> 1;
  const int wko = (t & 1) * 16;
  const int ab0 = wko >> 3;
  const int aswz = (wco >> 3) & 3;

  const int lane = t & 63;
  const int l15 = lane & 15;
  const int q = lane >> 4;
  const int wv = t >> 6;
  const int wy = wv >> 1;
  const int wx = wv & 1;

  f32x4 acc[4][4] = {};

  // prologue: load k=0 slice into registers
  u16x8 a0 = *(const u16x8*)(wq1 + wco * C1 + wko);
  u16x8 a1 = *(const u16x8*)(wq1 + wco * C1 + wko + 8);
  f32x4 va0 = *(const f32x4*)(xA + kk * HW);
  f32x4 va1 = *(const f32x4*)(xA + kk * HW + 4);
  f32x4 vb0 = *(const f32x4*)(xB + kk * HW);
  f32x4 vb1 = *(const f32x4*)(xB + kk * HW + 4);
  float inv = bn1i[kk], bb = bn1b[kk];

#pragma unroll 1
  for (int i = 0; i < 16; i++) {
    const int cur = i & 1;
    // write staged regs into LDS[cur]
    *(u16x8*)&Alds[cur][wco * 40 + (((ab0 + 0 + aswz) & 3) << 3)] = a0;
    *(u16x8*)&Alds[cur][wco * 40 + (((ab0 + 1 + aswz) & 3) << 3)] = a1;
#pragma unroll
    for (int j = 0; j < 4; j++) {
      float f0 = fmaxf(fmaf(va0[j], inv, bb), 0.0f);
      Blds[cur][(spA + j) * 40 + colg] = f2bf(fmaf(rintf((f0 - mn1) * r1), s1, mn1));
      float f1 = fmaxf(fmaf(va1[j], inv, bb), 0.0f);
      Blds[cur][(spA + 4 + j) * 40 + colg] = f2bf(fmaf(rintf((f1 - mn1) * r1), s1, mn1));
      float g0 = fmaxf(fmaf(vb0[j], inv, bb), 0.0f);
      Blds[cur][(spB + j) * 40 + colg] = f2bf(fmaf(rintf((g0 - mn1) * r1), s1, mn1));
      float g1v = fmaxf(fmaf(vb1[j], inv, bb), 0.0f);
      Blds[cur][(spB + 4 + j) * 40 + colg] = f2bf(fmaf(rintf((g1v - mn1) * r1), s1, mn1));
    }
    // prefetch k-slice i+1 into registers (in flight across barrier + MFMA)
    if (i < 15) {
      const int kn = (i + 1) * 32;
      a0 = *(const u16x8*)(wq1 + wco * C1 + kn + wko);
      a1 = *(const u16x8*)(wq1 + wco * C1 + kn + wko + 8);
      const int c = kn + kk;
      va0 = *(const f32x4*)(xA + c * HW);
      va1 = *(const f32x4*)(xA + c * HW + 4);
      vb0 = *(const f32x4*)(xB + c * HW);
      vb1 = *(const f32x4*)(xB + c * HW + 4);
      inv = bn1i[c]; bb = bn1b[c];
    }
    __syncthreads();
    bf16x8 af[4], bfr[4];
#pragma unroll
    for (int ii = 0; ii < 4; ii++) {
      int R = wy * 64 + ii * 16 + l15;
      af[ii] = *(const bf16x8*)&Alds[cur][R * 40 + (((q + (R >> 3)) & 3) << 3)];
    }
#pragma unroll
    for (int j = 0; j < 4; j++) {
      int R = wx * 64 + j * 16 + l15;
      bfr[j] = *(const bf16x8*)&Blds[cur][R * 40 + (((q + (R >> 3)) & 3) << 3)];
    }
#pragma unroll
    for (int ii = 0; ii < 4; ii++)
#pragma unroll
      for (int j = 0; j < 4; j++)
        acc[ii][j] = __builtin_amdgcn_mfma_f32_16x16x32_bf16(af[ii], bfr[j], acc[ii][j], 0, 0, 0);
  }

  // epilogue: bn2 + relu, store raw h2 NHWC bf16, per-block min/max partial
  float lmn = 3.4e38f, lmx = 0.0f;
#pragma unroll
  for (int i = 0; i < 4; i++) {
    int cob = wy * 64 + i * 16 + q * 4;
    f32x4 i2 = *(const f32x4*)&bn2i[cob];
    f32x4 b2 = *(const f32x4*)&bn2b[cob];
#pragma unroll
    for (int j = 0; j < 4; j++) {
      int sp = sp0 + wx * 64 + j * 16 + l15;
      u16x4 v;
#pragma unroll
      for (int r = 0; r < 4; r++) {
        float h = fmaxf(fmaf(acc[i][j][r], i2[r], b2[r]), 0.0f);
        v[r] = f2bf(h);
        lmn = fminf(lmn, h); lmx = fmaxf(lmx, h);
      }
      *(u16x4*)&h2[sp * C2 + cob] = v;
    }
  }
  for (int m = 32; m; m >>= 1) {
    lmn = fminf(lmn, __shfl_xor(lmn, m));
    lmx = fmaxf(lmx, __shfl_xor(lmx, m));
  }
  if (lane == 0) { wred[wv] = lmn; wred[4 + wv] = lmx; }
  __syncthreads();
  if (t == 0) {
    float2 pr;
    pr.x = fminf(fminf(wred[0], wred[1]), fminf(wred[2], wred[3]));
    pr.y = fmaxf(fmaxf(wred[4], wred[5]), fmaxf(wred[6], wred[7]));
    p2[blockIdx.x] = pr;
  }
}

// ---------------------------------------------------------------------------
// conv2: 3x3 conv (pad 1) direct MFMA, inline h2 quant, XCD-aware swizzle:
// sblk = (B&7)*98 + (B>>3) gives each XCD a contiguous 1/8 of h2 (1.6 MB,
// L2-resident) instead of streaming all 12.8 MB through every XCD's L2.
// ---------------------------------------------------------------------------
__global__ __launch_bounds__(256) void conv2_kernel(const unsigned char* ws,
                                                    float* __restrict__ out) {
  const u16* wq2 = (const u16*)(ws + WS_WQ2);
  const u16* h2 = (const u16*)(ws + WS_H2);
  const float2* p2 = (const float2*)(ws + WS_P2);
  __shared__ float bc2[2];

  const int t = threadIdx.x;
  {  // preamble: reduce 392 conv1-partials
    float mn = 3.4e38f, mx = 0.0f;
    for (int i = t; i < CONV1_BLOCKS; i += 256) {
      float2 p = p2[i];
      mn = fminf(mn, p.x); mx = fmaxf(mx, p.y);
    }
    block_minmax(mn, mx);
    if (t == 0) { bc2[0] = mn; bc2[1] = mx; }
    __syncthreads();
  }
  const float mn2 = bc2[0];
  const float s2 = fmaxf((bc2[1] - mn2) / 255.0f, 1e-8f);
  const float r2 = 1.0f / s2;

  const int lane = t & 63;
  const int l15 = lane & 15;
  const int q = lane >> 4;
  const int wv = t >> 6;

  const int B = blockIdx.x;
  const int sblk = (B & 7) * 98 + (B >> 3);    // XCD-contiguous sp mapping
  const int spf = sblk * 64 + wv * 16 + l15;
  const int nn = spf / HW;
  const int hwf = spf % HW;
  const int hf = hwf / WW;
  const int wf = hwf % WW;

  f32x4 acc[2] = {};
  bf16x8 bz;
#pragma unroll
  for (int j = 0; j < 8; j++) bz[j] = 0;

  for (int tap = 0; tap < 9; tap++) {
    const int dh = tap / 3 - 1, dw = tap % 3 - 1;
    const u16* wA = wq2 + tap * (C3 * C2);
    unsigned h2i = (unsigned)(hf + dh);
    unsigned w2i = (unsigned)(wf + dw);
    const bool val = (h2i < 28u) && (w2i < 28u);
    const u16* bptr = h2 + ((size_t)(nn * HW + (int)h2i * WW + (int)w2i)) * C2;
#pragma unroll
    for (int ks = 0; ks < C2; ks += 32) {
      bf16x8 a[2], b;
#pragma unroll
      for (int f = 0; f < 2; f++)
        a[f] = *(const bf16x8*)(wA + (f * 16 + l15) * C2 + ks + q * 8);
      if (val) {
        u16x8 hv = *(const u16x8*)(bptr + ks + q * 8);
#pragma unroll
        for (int j = 0; j < 8; j++) {
          float h = bf2f(hv[j]);
          b[j] = (short)f2bf(fmaf(rintf((h - mn2) * r2), s2, mn2));
        }
      } else {
        b = bz;
      }
#pragma unroll
      for (int i = 0; i < 2; i++)
        acc[i] = __builtin_amdgcn_mfma_f32_16x16x32_bf16(a[i], b, acc[i], 0, 0, 0);
    }
  }

#pragma unroll
  for (int i = 0; i < 2; i++) {
    int co = i * 16 + q * 4;
#pragma unroll
    for (int r = 0; r < 4; r++)
      out[(nn * C3 + co + r) * HW + hwf] = acc[i][r];
  }
}

// ---------------------------------------------------------------------------
extern "C" void kernel_launch(void* const* d_in, const int* in_sizes, int n_in,
                              void* d_out, int out_size, void* d_ws, size_t ws_size,
                              hipStream_t stream) {
  const float* x  = (const float*)d_in[0];
  const float* g1 = (const float*)d_in[1];
  const float* b1 = (const float*)d_in[2];
  const float* m1 = (const float*)d_in[3];
  const float* v1 = (const float*)d_in[4];
  const float* w1 = (const float*)d_in[5];
  const float* g2 = (const float*)d_in[6];
  const float* b2 = (const float*)d_in[7];
  const float* m2 = (const float*)d_in[8];
  const float* v2 = (const float*)d_in[9];
  const float* w2 = (const float*)d_in[10];
  unsigned char* ws = (unsigned char*)d_ws;
  float* out = (float*)d_out;

  kwA_kernel<<<81, 256, 0, stream>>>(g1, b1, m1, v1, w1, g2, b2, m2, v2, w2, ws);
  kwB_kernel<<<80, 256, 0, stream>>>(w1, w2, ws);
  k1_minmax<<<K1_BLOCKS, 256, 0, stream>>>(x, ws);
  conv1_kernel<<<CONV1_BLOCKS, 256, 0, stream>>>(x, ws);
  conv2_kernel<<<CONV2_BLOCKS, 256, 0, stream>>>(ws, out);
}